// Round 8
// baseline (219.720 us; speedup 1.0000x reference)
//
#include <hip/hip_runtime.h>
#include <stdint.h>

#define N    4096
#define EMB  256
#define NH   4
#define HC   64     // channels per head
#define PAD  40     // LDS inner stride (elements): 80B = 20 banks -> <=2-way

typedef __attribute__((ext_vector_type(8))) short s16x8;   // 8 bf16 frag
typedef __attribute__((ext_vector_type(4))) short s16x4;
typedef __attribute__((ext_vector_type(4))) float f32x4;
typedef __attribute__((ext_vector_type(4))) int   i32x4;
typedef unsigned short ushort_t;

__device__ __forceinline__ unsigned short f2bf(float f) {
  unsigned int u = __builtin_bit_cast(unsigned int, f);
  u += 0x7fffu + ((u >> 16) & 1u);      // RNE (finite values only)
  return (unsigned short)(u >> 16);
}

// ---------------- K0: W[k][m] -> k-panel bf16 layout WP[k/32][m][k%32] ------
__global__ void k_transpose_bf(const float* __restrict__ W0, ushort_t* __restrict__ WP0,
                               const float* __restrict__ W1, ushort_t* __restrict__ WP1) {
  int k = blockIdx.x & 255;
  int m = threadIdx.x;
  unsigned short v;
  size_t dst = ((size_t)(k >> 5) * 256 + m) * 32 + (k & 31);
  if (blockIdx.x < 256) { v = f2bf(W0[k * EMB + m]); WP0[dst] = v; }
  else                  { v = f2bf(W1[k * EMB + m]); WP1[dst] = v; }
}

// ---------------- K2: pack adjacency to transposed bitmask (ballot) --------
__global__ __launch_bounds__(256)
void k2_pack(const int* __restrict__ adj, unsigned int* __restrict__ abits) {
  const int w = threadIdx.x >> 6, lane = threadIdx.x & 63;
  const int i = blockIdx.x * 4 + w;
  const int* row = adj + (size_t)i * N;
  #pragma unroll 2
  for (int c = 0; c < 64; ++c) {
    int v = row[c * 64 + lane];
    unsigned long long m = __ballot(v != 0);
    if ((i >> 6) == c) m |= 1ull << (i & 63);
    if (lane == 0)      abits[(size_t)(2 * c)     * N + i] = (unsigned int)m;
    else if (lane == 1) abits[(size_t)(2 * c + 1) * N + i] = (unsigned int)(m >> 32);
  }
}

// ---------------- K1: h = x @ W_lin (bf16 MFMA) ----------------------------
__global__ __launch_bounds__(256, 2)
void k1_gemm_h(const float* __restrict__ x,
               const ushort_t* __restrict__ WlP,      // [8][256][32] k-panels
               const float* __restrict__ att_src,     // [4][64]
               const float* __restrict__ att_dst,
               ushort_t* __restrict__ hS,             // [4][128][64][32]
               float* __restrict__ a_srcT,            // [4][4096]
               float* __restrict__ a_dstT)
{
  __shared__ ushort_t A_lds[32][PAD];
  __shared__ ushort_t B_lds[64][PAD];
  __shared__ ushort_t T_lds[64][PAD];   // [c][node 0..31]
  __shared__ float red_lds[2][2][32];   // [src/dst][chalf][node]
  const int t = threadIdx.x;
  const int lane = t & 63;
  const int w = t >> 6;
  const int ihalf = w & 1, chalf = w >> 1;
  const int i0 = blockIdx.x * 32;
  const int head = blockIdx.y;
  const int c0 = head * 64;
  const int lq = lane >> 4, lm = lane & 15;

  f32x4 acc[2];
  acc[0] = f32x4{0.f, 0.f, 0.f, 0.f};
  acc[1] = f32x4{0.f, 0.f, 0.f, 0.f};

  for (int kp = 0; kp < 8; ++kp) {
    __syncthreads();
    {
      int row = t >> 3, ko = (t & 7) * 4;
      f32x4 v = *(const f32x4*)(x + (size_t)(i0 + row) * EMB + kp * 32 + ko);
      s16x4 pk;
      pk[0] = (short)f2bf(v[0]); pk[1] = (short)f2bf(v[1]);
      pk[2] = (short)f2bf(v[2]); pk[3] = (short)f2bf(v[3]);
      *(s16x4*)&A_lds[row][ko] = pk;
      *(s16x8*)&B_lds[t >> 2][(t & 3) * 8] =
          *(const s16x8*)(WlP + (size_t)kp * 8192 + (size_t)c0 * 32 + t * 8);
    }
    __syncthreads();
    s16x8 a = *(const s16x8*)&A_lds[ihalf * 16 + lm][lq * 8];
    #pragma unroll
    for (int nf = 0; nf < 2; ++nf) {
      s16x8 b = *(const s16x8*)&B_lds[chalf * 32 + nf * 16 + lm][lq * 8];
      acc[nf] = __builtin_amdgcn_mfma_f32_16x16x32_bf16(a, b, acc[nf], 0, 0, 0);
    }
  }

  float ps[4] = {0.f,0.f,0.f,0.f}, pd[4] = {0.f,0.f,0.f,0.f};
  #pragma unroll
  for (int nf = 0; nf < 2; ++nf) {
    int c = chalf * 32 + nf * 16 + lm;
    float wsv = att_src[c0 + c];
    float wdv = att_dst[c0 + c];
    #pragma unroll
    for (int r = 0; r < 4; ++r) {
      float v = acc[nf][r];                 // D: row=lq*4+r, col=lm
      T_lds[c][ihalf * 16 + lq * 4 + r] = f2bf(v);
      ps[r] += v * wsv;
      pd[r] += v * wdv;
    }
  }
  #pragma unroll
  for (int r = 0; r < 4; ++r) {
    #pragma unroll
    for (int mm = 1; mm < 16; mm <<= 1) {
      ps[r] += __shfl_xor(ps[r], mm);
      pd[r] += __shfl_xor(pd[r], mm);
    }
  }
  if (lm == 0) {
    #pragma unroll
    for (int r = 0; r < 4; ++r) {
      int node = ihalf * 16 + lq * 4 + r;
      red_lds[0][chalf][node] = ps[r];
      red_lds[1][chalf][node] = pd[r];
    }
  }
  __syncthreads();
  if (t < 32) {
    a_srcT[head * N + i0 + t] = red_lds[0][0][t] + red_lds[0][1][t];
    a_dstT[head * N + i0 + t] = red_lds[1][0][t] + red_lds[1][1][t];
  }
  {
    int c = t >> 2, seg = t & 3;
    s16x8 v = *(const s16x8*)&T_lds[c][seg * 8];
    size_t base = (((size_t)head * 128 + (i0 >> 5)) * 64 + c) * 32 + seg * 8;
    *(s16x8*)(hS + base) = v;
  }
}

// ---------------- K34: fused masked-softmax attention, atomic-free ---------
// R7 structure (1 head, 8 j-eighths, grid (256,4)=1024 -> 4 blocks/CU) with
// R6's register budget: __launch_bounds__(512,2) -> VGPR cap 128.
// R7 lesson: (512,4) capped VGPR at 64 -> compiler serialized the loads
// (VALUBusy 46->31%, 44->64us). Occupancy comes from the grid; ILP from regs.
// Denominator via mfma(af, ones). Static indexing only.
__global__ __launch_bounds__(512, 2)
void k34_attn(const unsigned int* __restrict__ abits, // [128 jw][4096 i]
              const ushort_t* __restrict__ hS,        // [4][128][64][32]
              const float* __restrict__ a_srcT,       // [4][4096]
              const float* __restrict__ a_dstT,       // [4][4096]
              const float* __restrict__ bias_att,     // [256]
              ushort_t* __restrict__ oat)             // [4096][256]
{
  __shared__ float acc_lds[7][16][65];     // jq=1..7 partials
  __shared__ float l_lds[8][16];

  const int t = threadIdx.x;
  const int lane = t & 63;
  const int jq = t >> 6;           // 0..7 = j-eighth
  const int head = blockIdx.y;
  const int i0 = blockIdx.x * 16;
  const int lm = lane & 15, lq = lane >> 4;
  const int ig = i0 + lm;          // this lane's A-row (i)

  const float* asrc_h = a_srcT + head * N;
  const ushort_t* hS_h = hS + (size_t)head * 128 * 64 * 32;
  const float ad = a_dstT[head * N + ig];

  f32x4 acc[4];
  #pragma unroll
  for (int nf = 0; nf < 4; ++nf) acc[nf] = f32x4{0.f, 0.f, 0.f, 0.f};
  f32x4 accl = f32x4{0.f, 0.f, 0.f, 0.f};
  s16x8 ones;
  #pragma unroll
  for (int u = 0; u < 8; ++u) ones[u] = (short)0x3F80;   // bf16 1.0

  #pragma unroll 2
  for (int it = 0; it < 16; ++it) {
    const int jw = jq * 16 + it;               // j-window (32 j's)
    const int jl = jw * 32 + lq * 8;           // this lane's first j

    unsigned int word = abits[(size_t)jw * N + ig];      // coalesced 64B
    f32x4 as0 = *(const f32x4*)(asrc_h + jl);
    f32x4 as1 = *(const f32x4*)(asrc_h + jl + 4);

    const ushort_t* tile = hS_h + (size_t)jw * 2048;     // [64 c][32 j]
    s16x8 b0 = *(const s16x8*)(tile + ( 0 + lm) * 32 + lq * 8);
    s16x8 b1 = *(const s16x8*)(tile + (16 + lm) * 32 + lq * 8);
    s16x8 b2 = *(const s16x8*)(tile + (32 + lm) * 32 + lq * 8);
    s16x8 b3 = *(const s16x8*)(tile + (48 + lm) * 32 + lq * 8);

    unsigned int ebits[8];
    #pragma unroll
    for (int jj = 0; jj < 8; ++jj) {
      float asv = (jj < 4) ? as0[jj] : as1[jj - 4];
      float sc = asv + ad;
      sc = fmaxf(sc, 0.2f * sc);                         // leaky relu
      bool con = (word >> (lq * 8 + jj)) & 1u;           // adj + self-loop
      float e = con ? __expf(sc) : 0.f;
      ebits[jj] = __builtin_bit_cast(unsigned int, e) & 0xffff0000u; // trunc bf16
    }
    i32x4 pk;
    #pragma unroll
    for (int u = 0; u < 4; ++u)
      pk[u] = (int)__builtin_amdgcn_perm(ebits[2 * u + 1], ebits[2 * u], 0x07060302u);
    s16x8 af = __builtin_bit_cast(s16x8, pk);

    acc[0] = __builtin_amdgcn_mfma_f32_16x16x32_bf16(af, b0, acc[0], 0, 0, 0);
    acc[1] = __builtin_amdgcn_mfma_f32_16x16x32_bf16(af, b1, acc[1], 0, 0, 0);
    acc[2] = __builtin_amdgcn_mfma_f32_16x16x32_bf16(af, b2, acc[2], 0, 0, 0);
    acc[3] = __builtin_amdgcn_mfma_f32_16x16x32_bf16(af, b3, acc[3], 0, 0, 0);
    accl   = __builtin_amdgcn_mfma_f32_16x16x32_bf16(af, ones, accl, 0, 0, 0);
  }

  // accl[r] = this eighth's denominator for row lq*4+r (replicated over cols)
  if (lm == 0) {
    #pragma unroll
    for (int r = 0; r < 4; ++r) l_lds[jq][lq * 4 + r] = accl[r];
  }
  if (jq != 0) {
    #pragma unroll
    for (int nf = 0; nf < 4; ++nf)
      #pragma unroll
      for (int r = 0; r < 4; ++r)
        acc_lds[jq - 1][lq * 4 + r][nf * 16 + lm] = acc[nf][r];
  }
  __syncthreads();
  if (jq == 0) {
    float linv[4];
    #pragma unroll
    for (int r = 0; r < 4; ++r) {
      int row = lq * 4 + r;
      float s = 0.f;
      #pragma unroll
      for (int q = 0; q < 8; ++q) s += l_lds[q][row];
      linv[r] = 1.f / s;
    }
    #pragma unroll
    for (int nf = 0; nf < 4; ++nf) {
      float bia = bias_att[head * 64 + nf * 16 + lm];
      #pragma unroll
      for (int r = 0; r < 4; ++r) {
        int row = lq * 4 + r;
        float v = acc[nf][r];
        #pragma unroll
        for (int q = 0; q < 7; ++q) v += acc_lds[q][row][nf * 16 + lm];
        oat[(size_t)(i0 + row) * EMB + head * 64 + nf * 16 + lm] = f2bf(v * linv[r] + bia);
      }
    }
  }
}

// ---------------- K5: y = oat @ W_out + b_out, then LayerNorm -------------
// Barrier-free K-loop: A frags direct from L2-hot oat (16B/lane), B frags
// direct from k-panel WoP (1KB coalesced/inst, L2-resident 128KB). No LDS
// in the loop; one barrier for the LN epilogue. (Old k5: 16 barriers.)
__global__ __launch_bounds__(256, 2)
void k5_gemm_ln(const ushort_t* __restrict__ oat,    // [4096][256]
                const ushort_t* __restrict__ WoP,    // [8][256][32] k-panels
                const float* __restrict__ b_out,
                const float* __restrict__ gamma,
                const float* __restrict__ beta,
                float* __restrict__ out)
{
  __shared__ float y_lds[16][260];
  const int t = threadIdx.x, lane = t & 63, w = t >> 6;
  const int i0 = blockIdx.x * 16;
  const int lq = lane >> 4, lm = lane & 15;

  f32x4 acc[4];
  #pragma unroll
  for (int nf = 0; nf < 4; ++nf) acc[nf] = f32x4{0.f, 0.f, 0.f, 0.f};

  #pragma unroll 2
  for (int kp = 0; kp < 8; ++kp) {
    s16x8 a = *(const s16x8*)(oat + (size_t)(i0 + lm) * EMB + kp * 32 + lq * 8);
    s16x8 b0 = *(const s16x8*)(WoP + (size_t)kp * 8192 + (w * 64 +  0 + lm) * 32 + lq * 8);
    s16x8 b1 = *(const s16x8*)(WoP + (size_t)kp * 8192 + (w * 64 + 16 + lm) * 32 + lq * 8);
    s16x8 b2 = *(const s16x8*)(WoP + (size_t)kp * 8192 + (w * 64 + 32 + lm) * 32 + lq * 8);
    s16x8 b3 = *(const s16x8*)(WoP + (size_t)kp * 8192 + (w * 64 + 48 + lm) * 32 + lq * 8);
    acc[0] = __builtin_amdgcn_mfma_f32_16x16x32_bf16(a, b0, acc[0], 0, 0, 0);
    acc[1] = __builtin_amdgcn_mfma_f32_16x16x32_bf16(a, b1, acc[1], 0, 0, 0);
    acc[2] = __builtin_amdgcn_mfma_f32_16x16x32_bf16(a, b2, acc[2], 0, 0, 0);
    acc[3] = __builtin_amdgcn_mfma_f32_16x16x32_bf16(a, b3, acc[3], 0, 0, 0);
  }
  #pragma unroll
  for (int nf = 0; nf < 4; ++nf)
    #pragma unroll
    for (int r = 0; r < 4; ++r) {
      int row = lq * 4 + r;
      int col = w * 64 + nf * 16 + lm;
      y_lds[row][col] = acc[nf][r] + b_out[col];
    }
  __syncthreads();
  f32x4 g  = *(const f32x4*)(gamma + lane * 4);
  f32x4 be = *(const f32x4*)(beta + lane * 4);
  #pragma unroll
  for (int r = w * 4; r < w * 4 + 4; ++r) {
    f32x4 v = *(const f32x4*)&y_lds[r][lane * 4];
    float s1 = v[0] + v[1] + v[2] + v[3];
    float s2 = v[0]*v[0] + v[1]*v[1] + v[2]*v[2] + v[3]*v[3];
    #pragma unroll
    for (int mm = 1; mm < 64; mm <<= 1) { s1 += __shfl_xor(s1, mm); s2 += __shfl_xor(s2, mm); }
    float mu = s1 * (1.f / 256.f);
    float var = s2 * (1.f / 256.f) - mu * mu;
    float rs = rsqrtf(var + 1e-5f);
    f32x4 o;
    #pragma unroll
    for (int u = 0; u < 4; ++u) o[u] = (v[u] - mu) * rs * g[u] + be[u];
    *(f32x4*)(out + (size_t)(i0 + r) * EMB + lane * 4) = o;
  }
}

extern "C" void kernel_launch(void* const* d_in, const int* in_sizes, int n_in,
                              void* d_out, int out_size, void* d_ws, size_t ws_size,
                              hipStream_t stream)
{
  (void)in_sizes; (void)n_in; (void)out_size; (void)ws_size;
  const float* x        = (const float*)d_in[0];
  const int*   adj      = (const int*)d_in[1];
  const float* W_lin    = (const float*)d_in[2];
  const float* att_src  = (const float*)d_in[3];
  const float* att_dst  = (const float*)d_in[4];
  const float* bias_att = (const float*)d_in[5];
  const float* W_out    = (const float*)d_in[6];
  const float* b_out    = (const float*)d_in[7];
  const float* gamma    = (const float*)d_in[8];
  const float* beta     = (const float*)d_in[9];
  float* out = (float*)d_out;

  uint8_t* p = (uint8_t*)d_ws;
  ushort_t* WlP = (ushort_t*)p;  p += (size_t)EMB * EMB * sizeof(ushort_t);
  ushort_t* WoP = (ushort_t*)p;  p += (size_t)EMB * EMB * sizeof(ushort_t);
  ushort_t* hS  = (ushort_t*)p;  p += (size_t)NH * HC * N * sizeof(ushort_t);
  float* a_srcb = (float*)p;     p += (size_t)NH * N * sizeof(float);
  float* a_dstb = (float*)p;     p += (size_t)NH * N * sizeof(float);
  ushort_t* oat = (ushort_t*)p;  p += (size_t)N * EMB * sizeof(ushort_t);
  unsigned int* abits = (unsigned int*)p; p += (size_t)(N / 32) * N * sizeof(unsigned int);

  k_transpose_bf<<<2 * EMB, EMB, 0, stream>>>(W_lin, WlP, W_out, WoP);
  k2_pack<<<N / 4, 256, 0, stream>>>(adj, abits);
  k1_gemm_h<<<dim3(N / 32, NH), 256, 0, stream>>>(x, WlP, att_src, att_dst, hS, a_srcb, a_dstb);
  k34_attn<<<dim3(N / 16, NH), 512, 0, stream>>>(abits, hS, a_srcb, a_dstb, bias_att, oat);
  k5_gemm_ln<<<N / 16, 256, 0, stream>>>(oat, WoP, b_out, gamma, beta, out);
}

// Round 9
// 203.725 us; speedup vs baseline: 1.0785x; 1.0785x over previous
//
#include <hip/hip_runtime.h>
#include <stdint.h>

#define N    4096
#define EMB  256
#define NH   4
#define HC   64     // channels per head
#define PAD  40     // LDS inner stride (elements): 80B = 20 banks -> <=2-way

typedef __attribute__((ext_vector_type(8))) short s16x8;   // 8 bf16 frag
typedef __attribute__((ext_vector_type(4))) short s16x4;
typedef __attribute__((ext_vector_type(4))) float f32x4;
typedef __attribute__((ext_vector_type(4))) int   i32x4;
typedef unsigned short ushort_t;

__device__ __forceinline__ unsigned short f2bf(float f) {
  unsigned int u = __builtin_bit_cast(unsigned int, f);
  u += 0x7fffu + ((u >> 16) & 1u);      // RNE (finite values only)
  return (unsigned short)(u >> 16);
}

// ---------------- K_prep: fused weight-transpose + adjacency bitmask -------
// blocks 0..1023: pack adj row-group -> abits[jw][i] (ballot, coalesced 256B
// reads). blocks 1024..1535: W[k][m] -> k-panel bf16 WP[k/32][m][k%32].
// Block-uniform branch; one dispatch instead of two.
__global__ __launch_bounds__(256)
void k_prep(const float* __restrict__ W0, ushort_t* __restrict__ WP0,
            const float* __restrict__ W1, ushort_t* __restrict__ WP1,
            const int* __restrict__ adj, unsigned int* __restrict__ abits)
{
  int b = blockIdx.x;
  if (b < 1024) {
    const int w = threadIdx.x >> 6, lane = threadIdx.x & 63;
    const int i = b * 4 + w;
    const int* row = adj + (size_t)i * N;
    #pragma unroll 4
    for (int c = 0; c < 64; ++c) {
      int v = row[c * 64 + lane];
      unsigned long long m = __ballot(v != 0);
      if ((i >> 6) == c) m |= 1ull << (i & 63);
      if (lane == 0)      abits[(size_t)(2 * c)     * N + i] = (unsigned int)m;
      else if (lane == 1) abits[(size_t)(2 * c + 1) * N + i] = (unsigned int)(m >> 32);
    }
  } else {
    b -= 1024;
    int k = b & 255;
    int m = threadIdx.x;
    size_t dst = ((size_t)(k >> 5) * 256 + m) * 32 + (k & 31);
    if (b < 256) WP0[dst] = f2bf(W0[k * EMB + m]);
    else         WP1[dst] = f2bf(W1[k * EMB + m]);
  }
}

// ---------------- K1: h = x @ W_lin (bf16 MFMA) ----------------------------
__global__ __launch_bounds__(256, 2)
void k1_gemm_h(const float* __restrict__ x,
               const ushort_t* __restrict__ WlP,      // [8][256][32] k-panels
               const float* __restrict__ att_src,     // [4][64]
               const float* __restrict__ att_dst,
               ushort_t* __restrict__ hS,             // [4][128][64][32]
               float* __restrict__ a_srcT,            // [4][4096]
               float* __restrict__ a_dstT)
{
  __shared__ ushort_t A_lds[32][PAD];
  __shared__ ushort_t B_lds[64][PAD];
  __shared__ ushort_t T_lds[64][PAD];   // [c][node 0..31]
  __shared__ float red_lds[2][2][32];   // [src/dst][chalf][node]
  const int t = threadIdx.x;
  const int lane = t & 63;
  const int w = t >> 6;
  const int ihalf = w & 1, chalf = w >> 1;
  const int i0 = blockIdx.x * 32;
  const int head = blockIdx.y;
  const int c0 = head * 64;
  const int lq = lane >> 4, lm = lane & 15;

  f32x4 acc[2];
  acc[0] = f32x4{0.f, 0.f, 0.f, 0.f};
  acc[1] = f32x4{0.f, 0.f, 0.f, 0.f};

  for (int kp = 0; kp < 8; ++kp) {
    __syncthreads();
    {
      int row = t >> 3, ko = (t & 7) * 4;
      f32x4 v = *(const f32x4*)(x + (size_t)(i0 + row) * EMB + kp * 32 + ko);
      s16x4 pk;
      pk[0] = (short)f2bf(v[0]); pk[1] = (short)f2bf(v[1]);
      pk[2] = (short)f2bf(v[2]); pk[3] = (short)f2bf(v[3]);
      *(s16x4*)&A_lds[row][ko] = pk;
      *(s16x8*)&B_lds[t >> 2][(t & 3) * 8] =
          *(const s16x8*)(WlP + (size_t)kp * 8192 + (size_t)c0 * 32 + t * 8);
    }
    __syncthreads();
    s16x8 a = *(const s16x8*)&A_lds[ihalf * 16 + lm][lq * 8];
    #pragma unroll
    for (int nf = 0; nf < 2; ++nf) {
      s16x8 b = *(const s16x8*)&B_lds[chalf * 32 + nf * 16 + lm][lq * 8];
      acc[nf] = __builtin_amdgcn_mfma_f32_16x16x32_bf16(a, b, acc[nf], 0, 0, 0);
    }
  }

  float ps[4] = {0.f,0.f,0.f,0.f}, pd[4] = {0.f,0.f,0.f,0.f};
  #pragma unroll
  for (int nf = 0; nf < 2; ++nf) {
    int c = chalf * 32 + nf * 16 + lm;
    float wsv = att_src[c0 + c];
    float wdv = att_dst[c0 + c];
    #pragma unroll
    for (int r = 0; r < 4; ++r) {
      float v = acc[nf][r];                 // D: row=lq*4+r, col=lm
      T_lds[c][ihalf * 16 + lq * 4 + r] = f2bf(v);
      ps[r] += v * wsv;
      pd[r] += v * wdv;
    }
  }
  #pragma unroll
  for (int r = 0; r < 4; ++r) {
    #pragma unroll
    for (int mm = 1; mm < 16; mm <<= 1) {
      ps[r] += __shfl_xor(ps[r], mm);
      pd[r] += __shfl_xor(pd[r], mm);
    }
  }
  if (lm == 0) {
    #pragma unroll
    for (int r = 0; r < 4; ++r) {
      int node = ihalf * 16 + lq * 4 + r;
      red_lds[0][chalf][node] = ps[r];
      red_lds[1][chalf][node] = pd[r];
    }
  }
  __syncthreads();
  if (t < 32) {
    a_srcT[head * N + i0 + t] = red_lds[0][0][t] + red_lds[0][1][t];
    a_dstT[head * N + i0 + t] = red_lds[1][0][t] + red_lds[1][1][t];
  }
  {
    int c = t >> 2, seg = t & 3;
    s16x8 v = *(const s16x8*)&T_lds[c][seg * 8];
    size_t base = (((size_t)head * 128 + (i0 >> 5)) * 64 + c) * 32 + seg * 8;
    *(s16x8*)(hS + base) = v;
  }
}

// ---------------- K34: fused masked-softmax attention, atomic-free ---------
// R6's proven shape (44us): 512 thr = 8 waves = (2 heads x 4 j-quarters),
// i-tile 16, grid (N/16, 2) = 512 blocks. R8 lesson: occupancy knobs don't
// move the needle (waves/CU pinned ~12-14 either way); per-wave ILP does
// (R6 VGPR=44 @44us vs R7/R8 VGPR=36 @60-64us). Single change vs R6:
// unroll 2 -> 3 (more loads in flight; ~100 VGPR est, cap 128 via (512,2)).
__global__ __launch_bounds__(512, 2)
void k34_attn(const unsigned int* __restrict__ abits, // [128 jw][4096 i]
              const ushort_t* __restrict__ hS,        // [4][128][64][32]
              const float* __restrict__ a_srcT,       // [4][4096]
              const float* __restrict__ a_dstT,       // [4][4096]
              const float* __restrict__ bias_att,     // [256]
              ushort_t* __restrict__ oat)             // [4096][256]
{
  __shared__ float acc_lds[2][3][16][65];  // jq=1..3 partials per local head
  __shared__ float l_lds[2][4][16];

  const int t = threadIdx.x;
  const int lane = t & 63;
  const int w = t >> 6;            // 0..7
  const int hloc = w & 1;          // local head (of the pair)
  const int jq = w >> 1;           // j-quarter 0..3
  const int head = blockIdx.y * 2 + hloc;
  const int i0 = blockIdx.x * 16;
  const int lm = lane & 15, lq = lane >> 4;
  const int ig = i0 + lm;          // this lane's A-row (i)

  const float* asrc_h = a_srcT + head * N;
  const ushort_t* hS_h = hS + (size_t)head * 128 * 64 * 32;
  const float ad = a_dstT[head * N + ig];

  f32x4 acc[4];
  #pragma unroll
  for (int nf = 0; nf < 4; ++nf) acc[nf] = f32x4{0.f, 0.f, 0.f, 0.f};
  float lp = 0.f;

  #pragma unroll 3
  for (int it = 0; it < 32; ++it) {
    const int jw = jq * 32 + it;               // j-window (32 j's)
    const int jl = jw * 32 + lq * 8;           // this lane's first j

    unsigned int word = abits[(size_t)jw * N + ig];      // coalesced 64B
    f32x4 as0 = *(const f32x4*)(asrc_h + jl);
    f32x4 as1 = *(const f32x4*)(asrc_h + jl + 4);

    const ushort_t* tile = hS_h + (size_t)jw * 2048;     // [64 c][32 j]
    s16x8 b0 = *(const s16x8*)(tile + ( 0 + lm) * 32 + lq * 8);
    s16x8 b1 = *(const s16x8*)(tile + (16 + lm) * 32 + lq * 8);
    s16x8 b2 = *(const s16x8*)(tile + (32 + lm) * 32 + lq * 8);
    s16x8 b3 = *(const s16x8*)(tile + (48 + lm) * 32 + lq * 8);

    unsigned int ebits[8];
    #pragma unroll
    for (int jj = 0; jj < 8; ++jj) {
      float asv = (jj < 4) ? as0[jj] : as1[jj - 4];
      float sc = asv + ad;
      sc = fmaxf(sc, 0.2f * sc);                         // leaky relu
      bool con = (word >> (lq * 8 + jj)) & 1u;           // adj + self-loop
      float e = con ? __expf(sc) : 0.f;
      unsigned int eb = __builtin_bit_cast(unsigned int, e) & 0xffff0000u; // trunc bf16
      ebits[jj] = eb;
      lp += __builtin_bit_cast(float, eb);               // sum the SAME rounded value
    }
    i32x4 pk;
    #pragma unroll
    for (int u = 0; u < 4; ++u)
      pk[u] = (int)__builtin_amdgcn_perm(ebits[2 * u + 1], ebits[2 * u], 0x07060302u);
    s16x8 af = __builtin_bit_cast(s16x8, pk);

    acc[0] = __builtin_amdgcn_mfma_f32_16x16x32_bf16(af, b0, acc[0], 0, 0, 0);
    acc[1] = __builtin_amdgcn_mfma_f32_16x16x32_bf16(af, b1, acc[1], 0, 0, 0);
    acc[2] = __builtin_amdgcn_mfma_f32_16x16x32_bf16(af, b2, acc[2], 0, 0, 0);
    acc[3] = __builtin_amdgcn_mfma_f32_16x16x32_bf16(af, b3, acc[3], 0, 0, 0);
  }

  // denominator: quarter-row sum for row lm
  lp += __shfl_xor(lp, 16);
  lp += __shfl_xor(lp, 32);
  if (lq == 0) l_lds[hloc][jq][lm] = lp;

  // jq=1..3 park accumulators in LDS (C layout: row=lq*4+r, col=lm)
  if (jq != 0) {
    #pragma unroll
    for (int nf = 0; nf < 4; ++nf)
      #pragma unroll
      for (int r = 0; r < 4; ++r)
        acc_lds[hloc][jq - 1][lq * 4 + r][nf * 16 + lm] = acc[nf][r];
  }
  __syncthreads();
  if (jq == 0) {
    float linv[4];
    #pragma unroll
    for (int r = 0; r < 4; ++r) {
      int row = lq * 4 + r;
      linv[r] = 1.f / (l_lds[hloc][0][row] + l_lds[hloc][1][row] +
                       l_lds[hloc][2][row] + l_lds[hloc][3][row]);
    }
    #pragma unroll
    for (int nf = 0; nf < 4; ++nf) {
      float bia = bias_att[head * 64 + nf * 16 + lm];
      #pragma unroll
      for (int r = 0; r < 4; ++r) {
        int row = lq * 4 + r;
        float v = acc[nf][r] + acc_lds[hloc][0][row][nf * 16 + lm]
                             + acc_lds[hloc][1][row][nf * 16 + lm]
                             + acc_lds[hloc][2][row][nf * 16 + lm];
        oat[(size_t)(i0 + row) * EMB + head * 64 + nf * 16 + lm] = f2bf(v * linv[r] + bia);
      }
    }
  }
}

// ---------------- K5: y = oat @ W_out + b_out, then LayerNorm -------------
// LDS-staged B from k-panels (R7 provenance; R8 barrier-free variant was +5).
__global__ __launch_bounds__(256, 2)
void k5_gemm_ln(const ushort_t* __restrict__ oat,    // [4096][256]
                const ushort_t* __restrict__ WoP,    // [8][256][32] k-panels
                const float* __restrict__ b_out,
                const float* __restrict__ gamma,
                const float* __restrict__ beta,
                float* __restrict__ out)
{
  __shared__ ushort_t A_lds[16][PAD];
  __shared__ ushort_t B_lds[256][PAD];
  __shared__ float y_lds[16][260];
  const int t = threadIdx.x, lane = t & 63, w = t >> 6;
  const int i0 = blockIdx.x * 16;
  const int lq = lane >> 4, lm = lane & 15;

  f32x4 acc[4];
  #pragma unroll
  for (int nf = 0; nf < 4; ++nf) acc[nf] = f32x4{0.f, 0.f, 0.f, 0.f};

  for (int kp = 0; kp < 8; ++kp) {
    __syncthreads();
    if (t < 64) {
      int row = t >> 2, ko = (t & 3) * 8;
      *(s16x8*)&A_lds[row][ko] = *(const s16x8*)(oat + (size_t)(i0 + row) * EMB + kp * 32 + ko);
    }
    #pragma unroll
    for (int u = 0; u < 4; ++u)
      *(s16x8*)&B_lds[(t >> 2) + u * 64][(t & 3) * 8] =
          *(const s16x8*)(WoP + (size_t)kp * 8192 + u * 2048 + t * 8);
    __syncthreads();
    s16x8 a = *(const s16x8*)&A_lds[lm][lq * 8];
    #pragma unroll
    for (int nf = 0; nf < 4; ++nf) {
      s16x8 b = *(const s16x8*)&B_lds[w * 64 + nf * 16 + lm][lq * 8];
      acc[nf] = __builtin_amdgcn_mfma_f32_16x16x32_bf16(a, b, acc[nf], 0, 0, 0);
    }
  }
  #pragma unroll
  for (int nf = 0; nf < 4; ++nf)
    #pragma unroll
    for (int r = 0; r < 4; ++r) {
      int row = lq * 4 + r;
      int col = w * 64 + nf * 16 + lm;
      y_lds[row][col] = acc[nf][r] + b_out[col];
    }
  __syncthreads();
  f32x4 g  = *(const f32x4*)(gamma + lane * 4);
  f32x4 be = *(const f32x4*)(beta + lane * 4);
  #pragma unroll
  for (int r = w * 4; r < w * 4 + 4; ++r) {
    f32x4 v = *(const f32x4*)&y_lds[r][lane * 4];
    float s1 = v[0] + v[1] + v[2] + v[3];
    float s2 = v[0]*v[0] + v[1]*v[1] + v[2]*v[2] + v[3]*v[3];
    #pragma unroll
    for (int mm = 1; mm < 64; mm <<= 1) { s1 += __shfl_xor(s1, mm); s2 += __shfl_xor(s2, mm); }
    float mu = s1 * (1.f / 256.f);
    float var = s2 * (1.f / 256.f) - mu * mu;
    float rs = rsqrtf(var + 1e-5f);
    f32x4 o;
    #pragma unroll
    for (int u = 0; u < 4; ++u) o[u] = (v[u] - mu) * rs * g[u] + be[u];
    *(f32x4*)(out + (size_t)(i0 + r) * EMB + lane * 4) = o;
  }
}

extern "C" void kernel_launch(void* const* d_in, const int* in_sizes, int n_in,
                              void* d_out, int out_size, void* d_ws, size_t ws_size,
                              hipStream_t stream)
{
  (void)in_sizes; (void)n_in; (void)out_size; (void)ws_size;
  const float* x        = (const float*)d_in[0];
  const int*   adj      = (const int*)d_in[1];
  const float* W_lin    = (const float*)d_in[2];
  const float* att_src  = (const float*)d_in[3];
  const float* att_dst  = (const float*)d_in[4];
  const float* bias_att = (const float*)d_in[5];
  const float* W_out    = (const float*)d_in[6];
  const float* b_out    = (const float*)d_in[7];
  const float* gamma    = (const float*)d_in[8];
  const float* beta     = (const float*)d_in[9];
  float* out = (float*)d_out;

  uint8_t* p = (uint8_t*)d_ws;
  ushort_t* WlP = (ushort_t*)p;  p += (size_t)EMB * EMB * sizeof(ushort_t);
  ushort_t* WoP = (ushort_t*)p;  p += (size_t)EMB * EMB * sizeof(ushort_t);
  ushort_t* hS  = (ushort_t*)p;  p += (size_t)NH * HC * N * sizeof(ushort_t);
  float* a_srcb = (float*)p;     p += (size_t)NH * N * sizeof(float);
  float* a_dstb = (float*)p;     p += (size_t)NH * N * sizeof(float);
  ushort_t* oat = (ushort_t*)p;  p += (size_t)N * EMB * sizeof(ushort_t);
  unsigned int* abits = (unsigned int*)p; p += (size_t)(N / 32) * N * sizeof(unsigned int);

  k_prep<<<1536, 256, 0, stream>>>(W_lin, WlP, W_out, WoP, adj, abits);
  k1_gemm_h<<<dim3(N / 32, NH), 256, 0, stream>>>(x, WlP, att_src, att_dst, hS, a_srcb, a_dstb);
  k34_attn<<<dim3(N / 16, 2), 512, 0, stream>>>(abits, hS, a_srcb, a_dstb, bias_att, oat);
  k5_gemm_ln<<<N / 16, 256, 0, stream>>>(oat, WoP, b_out, gamma, beta, out);
}